// Round 8
// baseline (40.343 us; speedup 1.0000x reference)
//
#include <hip/hip_runtime.h>
#include <hip/hip_bf16.h>

#define NC 4096
#define NK 1024
#define NTI (NC / 64)    // 64 row tiles (64 rows each)
#define NTJ (NC / 128)   // 32 col tiles (128 cols each)
// live blocks: bi <= 2*bj+1 -> sum_{bj} (2*bj+2) = 1056 = 8 * 132
#define NBLK 1056
#define NPART 128        // scattered partial-sum slots (cacheline-spaced)

static constexpr float MARGIN = 0.0001f;

typedef __attribute__((ext_vector_type(4))) int i32x4;
typedef __attribute__((ext_vector_type(8))) int i32x8;
typedef __attribute__((ext_vector_type(16))) float f32x16;

// fp4 e2m1 quantize (round to nearest via thresholds): {0,.5,1,1.5,2,3,4,6}, sign bit 3.
__device__ inline uint q4(float x) {
    const float a = fabsf(x);
    uint c = (a >= 0.25f) + (a >= 0.75f) + (a >= 1.25f) + (a >= 1.75f) +
             (a >= 2.5f) + (a >= 3.5f) + (a >= 5.0f);
    return c | (x < 0.f ? 8u : 0u);
}

// Fragment-major fp4 layout: row r (group g=r>>5, rr=r&31), K-byte b=k>>1
// (chunk q=b>>5, half h=(b>>4)&1, lo=b&15):
//   addr = (g*16 + q)*1024 + (h*32 + rr)*16 + lo
// A wave's MFMA fragment (group g, chunk q) is the contiguous 1 KB at
// (g*16+q)*1024 + lane*16 -> one coalesced global_load_dwordx4, no LDS.
//
// 512 blocks x 4 waves; each wave quantizes 2 rows (8 elems -> one aligned
// uint store) + exact f32 row norm. Block 0 zeroes partials and the counter.
__global__ __launch_bounds__(256) void cast_sq_kernel(const float* __restrict__ x,
                                                      uchar* __restrict__ xq2,
                                                      float* __restrict__ sq,
                                                      float* __restrict__ part,
                                                      uint* __restrict__ counter) {
    const int tid = threadIdx.x, lane = tid & 63, wid = tid >> 6;
    if (blockIdx.x == 0) {
        if (tid < NPART) part[tid * 16] = 0.f;
        if (tid == NPART) *counter = 0u;
    }
    const int wg = blockIdx.x * 4 + wid;   // 2048 waves
    #pragma unroll
    for (int it = 0; it < 2; ++it) {
        const int row = wg + it * 2048;
        const int g = row >> 5, rr = row & 31;
        float s = 0.f;
        #pragma unroll
        for (int c = 0; c < 2; ++c) {
            // lane handles elements c*512 + 8*lane .. +7 (two adjacent float4)
            const float4 v0 = reinterpret_cast<const float4*>(x + (size_t)row * NK)[c * 128 + 2 * lane];
            const float4 v1 = reinterpret_cast<const float4*>(x + (size_t)row * NK)[c * 128 + 2 * lane + 1];
            s += v0.x * v0.x + v0.y * v0.y + v0.z * v0.z + v0.w * v0.w +
                 v1.x * v1.x + v1.y * v1.y + v1.z * v1.z + v1.w * v1.w;
            const uint u = q4(v0.x) | (q4(v0.y) << 4) | (q4(v0.z) << 8) | (q4(v0.w) << 12) |
                           (q4(v1.x) << 16) | (q4(v1.y) << 20) | (q4(v1.z) << 24) | (q4(v1.w) << 28);
            // output bytes b0 = c*256 + 4*lane (4-aligned within a 16B piece)
            const int q = 8 * c + (lane >> 3);
            const int h = (lane >> 2) & 1;
            const int lo = (lane & 3) * 4;
            *reinterpret_cast<uint*>(xq2 + (size_t)(g * 16 + q) * 1024 + (h * 32 + rr) * 16 + lo) = u;
        }
        #pragma unroll
        for (int off = 32; off > 0; off >>= 1) s += __shfl_down(s, off);
        if (lane == 0) sq[row] = s;
    }
}

// Upper-triangular tiled syrk in fp4 (scale 1.0) with fused hinge reduction
// and fused last-block final sum. NO LDS staging, no barriers in the K-loop:
// fragment-major layout -> every MFMA operand is one coalesced
// global_load_dwordx4 from the L2-resident 2 MB matrix. 64x128 tile, 4 waves;
// each wave: one A group (reused) x two B groups -> 2 independent MFMA chains.
__global__ __launch_bounds__(256, 4) void gram_hinge_kernel(const uchar* __restrict__ xq2,
                                                            const float* __restrict__ sq,
                                                            float* __restrict__ part,
                                                            uint* __restrict__ counter,
                                                            float* __restrict__ out) {
    // XCD-aware chunking: 1056 = 8 * 132 exactly -> bijective. Consecutive
    // wgid share the same B panel (bj run) -> per-XCD L2 locality.
    const int wgid = (blockIdx.x & 7) * (NBLK / 8) + (blockIdx.x >> 3);
    // Decode: runs of bi for each bj; run length = 2*bj+2 (bi in [0, 2*bj+1]).
    int rem = wgid;
    int bj = 0;
    while (rem >= 2 * bj + 2) { rem -= 2 * bj + 2; ++bj; }
    const int bi = rem;

    const int tid = threadIdx.x;
    const int lane = tid & 63, wid = tid >> 6;
    const int wr = wid >> 1, wc = wid & 1;   // 32-row half x 64-col half
    const int hi = lane >> 5;

    const int ga  = bi * 2 + wr;             // A row group (32 rows)
    const int gb0 = bj * 4 + wc * 2;         // two B col groups
    const int gb1 = gb0 + 1;
    const uchar* pa  = xq2 + (size_t)ga  * 16384 + lane * 16;
    const uchar* pb0 = xq2 + (size_t)gb0 * 16384 + lane * 16;
    const uchar* pb1 = xq2 + (size_t)gb1 * 16384 + lane * 16;

    f32x16 acc0, acc1;
    #pragma unroll
    for (int e = 0; e < 16; ++e) { acc0[e] = 0.f; acc1[e] = 0.f; }
    i32x8 av, bv0, bv1;
    #pragma unroll
    for (int e = 4; e < 8; ++e) { av[e] = 0; bv0[e] = 0; bv1[e] = 0; }

    #pragma unroll
    for (int q = 0; q < 16; ++q) {
        const i32x4 ta  = *reinterpret_cast<const i32x4*>(pa  + q * 1024);
        const i32x4 tb0 = *reinterpret_cast<const i32x4*>(pb0 + q * 1024);
        const i32x4 tb1 = *reinterpret_cast<const i32x4*>(pb1 + q * 1024);
        av[0] = ta[0]; av[1] = ta[1]; av[2] = ta[2]; av[3] = ta[3];
        bv0[0] = tb0[0]; bv0[1] = tb0[1]; bv0[2] = tb0[2]; bv0[3] = tb0[3];
        bv1[0] = tb1[0]; bv1[1] = tb1[1]; bv1[2] = tb1[2]; bv1[3] = tb1[3];
        acc0 = __builtin_amdgcn_mfma_scale_f32_32x32x64_f8f6f4(
            av, bv0, acc0, 4, 4, 0, 0x7f7f7f7f, 0, 0x7f7f7f7f);
        acc1 = __builtin_amdgcn_mfma_scale_f32_32x32x64_f8f6f4(
            av, bv1, acc1, 4, 4, 0, 0x7f7f7f7f, 0, 0x7f7f7f7f);
    }

    // Fused epilogue: d2 = sq[i] + sq[j] - 2*g ; hinge; mask i<j ; reduce.
    // C/D layout (32x32): col = lane&31, row = (r&3) + 8*(r>>2) + 4*(lane>>5)
    float local = 0.f;
    const int ibase = bi * 64 + wr * 32 + 4 * hi;
    const bool diag = (bi >= 2 * bj);   // tile touches the diagonal
    #pragma unroll
    for (int X = 0; X < 2; ++X) {
        const int jcol = bj * 128 + wc * 64 + X * 32 + (lane & 31);
        const float sqj = sq[jcol];
        const f32x16& a = X ? acc1 : acc0;
        if (!diag) {
            #pragma unroll
            for (int r = 0; r < 16; ++r) {
                const int i = ibase + (r & 3) + 8 * (r >> 2);
                const float d2 = sq[i] + sqj - 2.f * a[r];
                local += fmaxf(MARGIN - sqrtf(fmaxf(d2, 0.f)), 0.f);
            }
        } else {
            #pragma unroll
            for (int r = 0; r < 16; ++r) {
                const int i = ibase + (r & 3) + 8 * (r >> 2);
                if (i < jcol) {
                    const float d2 = sq[i] + sqj - 2.f * a[r];
                    local += fmaxf(MARGIN - sqrtf(fmaxf(d2, 0.f)), 0.f);
                }
            }
        }
    }
    #pragma unroll
    for (int off = 32; off > 0; off >>= 1) local += __shfl_down(local, off);
    __shared__ float red[4];
    __shared__ int lastflag;
    if (lane == 0) red[wid] = local;
    __syncthreads();
    if (tid == 0) {
        atomicAdd(&part[(wgid & (NPART - 1)) * 16], red[0] + red[1] + red[2] + red[3]);
        __threadfence();                                  // partial visible before counter
        lastflag = (atomicAdd(counter, 1u) == NBLK - 1);  // exactly one last block
    }
    __syncthreads();
    if (lastflag) {
        // Coherent cross-XCD read of partials via atomic RMW (+0).
        float v = (tid < NPART) ? atomicAdd(&part[tid * 16], 0.f) : 0.f;
        #pragma unroll
        for (int off = 32; off > 0; off >>= 1) v += __shfl_down(v, off);
        if (lane == 0) red[wid] = v;
        __syncthreads();
        if (tid == 0) out[0] = red[0] + red[1] + red[2] + red[3];
    }
}

extern "C" void kernel_launch(void* const* d_in, const int* in_sizes, int n_in,
                              void* d_out, int out_size, void* d_ws, size_t ws_size,
                              hipStream_t stream) {
    const float* x = (const float*)d_in[0];
    float* out = (float*)d_out;
    uchar* xq2 = (uchar*)d_ws;                                        // 2 MB fp4, fragment-major
    float* sq = (float*)((char*)d_ws + (size_t)NC * 512);             // 16 KB row norms
    float* part = (float*)((char*)d_ws + (size_t)NC * 512 + 16384);   // 8 KB partials
    uint* counter = (uint*)((char*)d_ws + (size_t)NC * 512 + 16384 + NPART * 64);

    cast_sq_kernel<<<512, 256, 0, stream>>>(x, xq2, sq, part, counter);
    gram_hinge_kernel<<<NBLK, 256, 0, stream>>>(xq2, sq, part, counter, out);
}

// Round 9
// 27.203 us; speedup vs baseline: 1.4830x; 1.4830x over previous
//
#include <hip/hip_runtime.h>
#include <hip/hip_bf16.h>

#define NC 4096
#define NK 1024
#define TS 64                      // tile size (rows and cols)
#define NT (NC / TS)               // 64 tiles per dim
#define NBLK (NT * (NT + 1) / 2)   // 2080 upper-triangular blocks = 8 XCDs * 260
#define NPART 128                  // scattered partial-sum slots (cacheline-spaced)

static constexpr float MARGIN = 0.0001f;

typedef __attribute__((ext_vector_type(4))) int i32x4;
typedef __attribute__((ext_vector_type(8))) int i32x8;
typedef __attribute__((ext_vector_type(16))) float f32x16;

// fp4 e2m1 quantize (round to nearest via thresholds): {0,.5,1,1.5,2,3,4,6}, sign bit 3.
__device__ inline uint q4(float x) {
    const float a = fabsf(x);
    uint c = (a >= 0.25f) + (a >= 0.75f) + (a >= 1.25f) + (a >= 1.75f) +
             (a >= 2.5f) + (a >= 3.5f) + (a >= 5.0f);
    return c | (x < 0.f ? 8u : 0u);
}

// Fragment-major fp4 layout: for row r (group g=r>>5, rr=r&31) and K-element k
// (byte b=k>>1, chunk q=b>>5, half h=(b>>4)&1, lo=b&15):
//   addr = (g*16 + q)*1024 + (h*32 + rr)*16 + lo
// A wave's MFMA fragment (group g, chunk q) is then the contiguous 1 KB at
// (g*16+q)*1024 + lane*16  -> one coalesced global_load_dwordx4, no LDS needed.
//
// 512 blocks x 4 waves; each wave quantizes 2 full rows and writes the exact
// f32 row norm. Block 0 also zeroes the partial slots.
__global__ __launch_bounds__(256) void cast_sq_kernel(const float* __restrict__ x,
                                                      uchar* __restrict__ xq2,
                                                      float* __restrict__ sq,
                                                      float* __restrict__ part) {
    const int tid = threadIdx.x, lane = tid & 63, wid = tid >> 6;
    if (blockIdx.x == 0 && tid < NPART) part[tid * 16] = 0.f;
    const int wg = blockIdx.x * 4 + wid;   // 2048 waves
    #pragma unroll
    for (int it = 0; it < 2; ++it) {
        const int row = wg + it * 2048;
        const int g = row >> 5, rr = row & 31;
        float s = 0.f;
        #pragma unroll
        for (int c = 0; c < 4; ++c) {
            const float4 v = reinterpret_cast<const float4*>(x + (size_t)row * NK)[lane + c * 64];
            s += v.x * v.x + v.y * v.y + v.z * v.z + v.w * v.w;
            const ushort u = (ushort)(q4(v.x) | (q4(v.y) << 4) | (q4(v.z) << 8) | (q4(v.w) << 12));
            // this ushort covers K-bytes b0..b0+1, b0 = 2*(lane + 64*c)
            const int q = 4 * c + (lane >> 4);
            const int h = (lane >> 3) & 1;
            const int lo = 2 * (lane & 7);
            *reinterpret_cast<ushort*>(xq2 + (size_t)(g * 16 + q) * 1024 + (h * 32 + rr) * 16 + lo) = u;
        }
        #pragma unroll
        for (int off = 32; off > 0; off >>= 1) s += __shfl_down(s, off);
        if (lane == 0) sq[row] = s;
    }
}

__global__ void final_kernel(const float* __restrict__ part, float* __restrict__ out) {
    float v = part[threadIdx.x * 16];
    #pragma unroll
    for (int off = 32; off > 0; off >>= 1) v += __shfl_down(v, off);
    __shared__ float r2[2];
    if ((threadIdx.x & 63) == 0) r2[threadIdx.x >> 6] = v;
    __syncthreads();
    if (threadIdx.x == 0) out[0] = r2[0] + r2[1];
}

// Upper-triangular tiled syrk in fp4 (scale 1.0) with fused hinge reduction.
// NO LDS, NO barriers: fragment-major layout makes every MFMA operand one
// coalesced global_load_dwordx4 from the L2-resident 2 MB matrix. Each of the
// 4 waves (2x2 quadrants of the 64x64 tile) is a straight line of 32
// independent loads + 16 chained MFMAs. launch_bounds(256,6) -> 6 blocks/CU
// resident (24 waves/CU): 1.5x the outstanding loads per SIMD vs round 7's 4.
__global__ __launch_bounds__(256, 6) void gram_hinge_kernel(const uchar* __restrict__ xq2,
                                                            const float* __restrict__ sq,
                                                            float* __restrict__ part) {
    // XCD-aware chunking: 2080 = 8 * 260 exactly -> bijective.
    const int wgid = (blockIdx.x & 7) * (NBLK / 8) + (blockIdx.x >> 3);
    // Closed-form triangular decode (runs of bj for each bi), +/-1 fixup.
    int b = (int)((129.0f - sqrtf((float)(16641 - 8 * wgid))) * 0.5f);
    while (wgid < b * NT - b * (b - 1) / 2) --b;
    while (wgid >= (b + 1) * NT - (b + 1) * b / 2) ++b;
    const int bi = b;
    const int bj = b + (wgid - (b * NT - b * (b - 1) / 2));

    const int tid = threadIdx.x;
    const int lane = tid & 63, wid = tid >> 6;
    const int wr = wid >> 1, wc = wid & 1;
    const int hi = lane >> 5;

    const int ga = bi * 2 + wr;   // 32-row group of this wave's A quadrant
    const int gb = bj * 2 + wc;
    const uchar* pa = xq2 + (size_t)ga * 16384 + lane * 16;
    const uchar* pb = xq2 + (size_t)gb * 16384 + lane * 16;

    f32x16 acc;
    #pragma unroll
    for (int e = 0; e < 16; ++e) acc[e] = 0.f;
    i32x8 av, bv;
    #pragma unroll
    for (int e = 4; e < 8; ++e) { av[e] = 0; bv[e] = 0; }

    #pragma unroll
    for (int q = 0; q < 16; ++q) {
        const i32x4 ta = *reinterpret_cast<const i32x4*>(pa + q * 1024);
        const i32x4 tb = *reinterpret_cast<const i32x4*>(pb + q * 1024);
        av[0] = ta[0]; av[1] = ta[1]; av[2] = ta[2]; av[3] = ta[3];
        bv[0] = tb[0]; bv[1] = tb[1]; bv[2] = tb[2]; bv[3] = tb[3];
        acc = __builtin_amdgcn_mfma_scale_f32_32x32x64_f8f6f4(
            av, bv, acc, 4, 4,                 // cbsz=fp4, blgp=fp4
            0, 0x7f7f7f7f, 0, 0x7f7f7f7f);     // scale = 1.0
    }

    // Fused epilogue: d2 = sq[i] + sq[j] - 2*g ; hinge; mask i<j ; reduce.
    // hinge > 0 iff d2 < MARGIN^2 (incl. d2<=0 clamp case) -> sqrt off the
    // common path; exactly equivalent to max(0, M - sqrt(max(d2,0))).
    // C/D layout (32x32): col = lane&31, row = (r&3) + 8*(r>>2) + 4*(lane>>5)
    float local = 0.f;
    const int jcol = bj * TS + wc * 32 + (lane & 31);
    const float sqj = sq[jcol];
    const int ibase = bi * TS + wr * 32 + 4 * hi;
    if (bi != bj) {
        #pragma unroll
        for (int r = 0; r < 16; ++r) {
            const int i = ibase + (r & 3) + 8 * (r >> 2);
            const float d2 = sq[i] + sqj - 2.f * acc[r];
            if (d2 < MARGIN * MARGIN) local += MARGIN - sqrtf(fmaxf(d2, 0.f));
        }
    } else {
        #pragma unroll
        for (int r = 0; r < 16; ++r) {
            const int i = ibase + (r & 3) + 8 * (r >> 2);
            const float d2 = sq[i] + sqj - 2.f * acc[r];
            if ((i < jcol) && (d2 < MARGIN * MARGIN)) local += MARGIN - sqrtf(fmaxf(d2, 0.f));
        }
    }
    #pragma unroll
    for (int off = 32; off > 0; off >>= 1) local += __shfl_down(local, off);
    __shared__ float red[4];
    if (lane == 0) red[wid] = local;
    __syncthreads();
    if (tid == 0) atomicAdd(&part[(wgid & (NPART - 1)) * 16],
                            red[0] + red[1] + red[2] + red[3]);
}

extern "C" void kernel_launch(void* const* d_in, const int* in_sizes, int n_in,
                              void* d_out, int out_size, void* d_ws, size_t ws_size,
                              hipStream_t stream) {
    const float* x = (const float*)d_in[0];
    float* out = (float*)d_out;
    uchar* xq2 = (uchar*)d_ws;                                       // 2 MB fp4, fragment-major
    float* sq = (float*)((char*)d_ws + (size_t)NC * 512);            // 16 KB row norms
    float* part = (float*)((char*)d_ws + (size_t)NC * 512 + 16384);  // 8 KB partials

    cast_sq_kernel<<<512, 256, 0, stream>>>(x, xq2, sq, part);
    gram_hinge_kernel<<<NBLK, 256, 0, stream>>>(xq2, sq, part);
    final_kernel<<<1, NPART, 0, stream>>>(part, out);
}